// Round 2
// baseline (392.957 us; speedup 1.0000x reference)
//
#include <hip/hip_runtime.h>
#include <math.h>

#define TINY_EPS 1.1920928955078125e-07f  // np.finfo(np.float32).eps = 2^-23

__device__ __forceinline__ float custom_round_f(float x) {
#pragma clang fp contract(off)
    float s = (x > 0.0f) ? 1.0f : ((x < 0.0f) ? -1.0f : 0.0f);
    float t = x - s * TINY_EPS;
    return floorf(t + 0.5f);
}

// g_x: given x and f = custom_round(x), flip the coordinate with the largest
// rounding error (first index on ties, matching np.argmax).
__device__ __forceinline__ void g_x8(const float* __restrict__ x,
                                     const float* __restrict__ f,
                                     float* __restrict__ out) {
#pragma clang fp contract(off)
    float best = -1.0f;
    int k = 0;
    float xk = 0.0f, fk = 0.0f;
#pragma unroll
    for (int j = 0; j < 8; ++j) {
        float d = fabsf(x[j] - f[j]);
        if (d > best) { best = d; k = j; xk = x[j]; fk = f[j]; }
    }
    float step;
    if (xk >= 0.0f) step = (fk < xk)  ? 1.0f : -1.0f;
    else            step = (fk <= xk) ? 1.0f : -1.0f;
#pragma unroll
    for (int j = 0; j < 8; ++j)
        out[j] = f[j] + ((j == k) ? step : 0.0f);
}

__device__ __forceinline__ void closest_point_E8(const float* __restrict__ x,
                                                 float* __restrict__ y) {
#pragma clang fp contract(off)
    // Branch 0: D8 via rounding
    float f[8], g0[8];
    float sumf = 0.0f;
#pragma unroll
    for (int j = 0; j < 8; ++j) { f[j] = custom_round_f(x[j]); sumf += f[j]; }
    g_x8(x, f, g0);
    bool even0 = ((((int)sumf) & 1) == 0);
    float y0[8];
#pragma unroll
    for (int j = 0; j < 8; ++j) y0[j] = even0 ? f[j] : g0[j];

    // Branch 1: D8 + 1/2
    float xs[8], fs[8], g1[8];
    float sumfs = 0.0f;
#pragma unroll
    for (int j = 0; j < 8; ++j) {
        xs[j] = x[j] - 0.5f;
        fs[j] = custom_round_f(xs[j]);
        sumfs += fs[j];
    }
    g_x8(xs, fs, g1);
    bool even1 = ((((int)sumfs) & 1) == 0);
    float y1[8];
#pragma unroll
    for (int j = 0; j < 8; ++j) y1[j] = (even1 ? fs[j] : g1[j]) + 0.5f;

    // Distances — numpy pairwise base-case tree to match the np reference
    float t0[8], t1[8];
#pragma unroll
    for (int j = 0; j < 8; ++j) {
        float d0 = x[j] - y0[j]; t0[j] = d0 * d0;
        float d1 = x[j] - y1[j]; t1[j] = d1 * d1;
    }
    float D0 = ((t0[0] + t0[1]) + (t0[2] + t0[3])) + ((t0[4] + t0[5]) + (t0[6] + t0[7]));
    float D1 = ((t1[0] + t1[1]) + (t1[2] + t1[3])) + ((t1[4] + t1[5]) + (t1[6] + t1[7]));
    bool pick0 = (D0 < D1);   // on tie, reference's where picks y1
#pragma unroll
    for (int j = 0; j < 8; ++j) y[j] = pick0 ? y0[j] : y1[j];
}

__global__ __launch_bounds__(256)
void lattice_quant_kernel(const float* __restrict__ x,
                          const float* __restrict__ beta_p,
                          const float* __restrict__ eps,
                          float* __restrict__ out, int n) {
#pragma clang fp contract(off)
    int row = blockIdx.x * blockDim.x + threadIdx.x;
    if (row >= n) return;
    float beta = beta_p[0];

    float xr[8];
    const float4* px = (const float4*)(x + (size_t)row * 8);
    float4 a0 = px[0], a1 = px[1];
    xr[0] = a0.x; xr[1] = a0.y; xr[2] = a0.z; xr[3] = a0.w;
    xr[4] = a1.x; xr[5] = a1.y; xr[6] = a1.z; xr[7] = a1.w;

    float xl[8];
#pragma unroll
    for (int j = 0; j < 8; ++j) xl[j] = xr[j] / beta;

    float xhat[8];
#pragma unroll
    for (int j = 0; j < 8; ++j) xhat[j] = 0.0f;

    float w = 1.0f;
#pragma unroll
    for (int l = 0; l < 3; ++l) {
        // ---- encode: quantize to E8 ----
        float xin[8], lat[8];
#pragma unroll
        for (int j = 0; j < 8; ++j) xin[j] = xl[j] + eps[j];
        closest_point_E8(xin, lat);

        // u = lat @ G_inv = inv(rows) @ lat  (forward substitution on the
        // lower-triangular `rows`; exact in fp32 — all values are multiples
        // of 0.25 with magnitude << 2^22, so order-insensitive and
        // bit-identical to the reference's dense fp32 matmul).
        // NOTE: u is NOT integer in general (u0 = lat0/2 can be x.5/x.25),
        // so custom_round below is load-bearing.
        float u[8];
        u[0] = 0.5f * lat[0];
#pragma unroll
        for (int k = 1; k <= 6; ++k) u[k] = lat[k] + u[k - 1];
        float s6 = ((u[0] + u[1]) + (u[2] + u[3])) + ((u[4] + u[5]) + u[6]);
        u[7] = 2.0f * lat[7] - s6;

        // b = custom_round(fmod(u, 4)) — fmod computed exactly (quarter-grid
        // values), then the reference's rounding applied.
        float b[8];
#pragma unroll
        for (int j = 0; j < 8; ++j) {
            float m = u[j] - truncf(u[j] * 0.25f) * 4.0f;  // == fmodf(u, 4)
            b[j] = custom_round_f(m);
        }

        // ---- decode this layer: Gb = b @ G.T = b @ rows (sparse, exact) ----
        float h = 0.5f * b[7];
        float Gb[8];
        Gb[0] = 2.0f * b[0] - b[1] + h;
#pragma unroll
        for (int j = 1; j <= 5; ++j) Gb[j] = b[j] - b[j + 1] + h;
        Gb[6] = b[6] + h;
        Gb[7] = h;

        float gq[8], cp[8];
#pragma unroll
        for (int j = 0; j < 8; ++j) gq[j] = Gb[j] * 0.25f;
        closest_point_E8(gq, cp);
#pragma unroll
        for (int j = 0; j < 8; ++j)
            xhat[j] += w * (Gb[j] - 4.0f * cp[j]);

        // next layer input: lat / Q (exact)
#pragma unroll
        for (int j = 0; j < 8; ++j) xl[j] = lat[j] * 0.25f;
        w *= 4.0f;
    }

    float4 o0, o1;
    o0.x = beta * xhat[0]; o0.y = beta * xhat[1];
    o0.z = beta * xhat[2]; o0.w = beta * xhat[3];
    o1.x = beta * xhat[4]; o1.y = beta * xhat[5];
    o1.z = beta * xhat[6]; o1.w = beta * xhat[7];
    float4* po = (float4*)(out + (size_t)row * 8);
    po[0] = o0; po[1] = o1;
}

extern "C" void kernel_launch(void* const* d_in, const int* in_sizes, int n_in,
                              void* d_out, int out_size, void* d_ws, size_t ws_size,
                              hipStream_t stream) {
    const float* x      = (const float*)d_in[0];
    const float* beta_p = (const float*)d_in[1];
    // d_in[2] = G, d_in[3] = G_inv — structure hardcoded (fixed by reference)
    const float* eps    = (const float*)d_in[4];
    float* out = (float*)d_out;
    int n = in_sizes[0] / 8;
    int block = 256;
    int grid = (n + block - 1) / block;
    lattice_quant_kernel<<<grid, block, 0, stream>>>(x, beta_p, eps, out, n);
}

// Round 4
// 363.143 us; speedup vs baseline: 1.0821x; 1.0821x over previous
//
#include <hip/hip_runtime.h>
#include <math.h>

#define TINY_EPS 1.1920928955078125e-07f  // np.finfo(np.float32).eps = 2^-23

// custom_round(x) = floor(x - sign(x)*TINY + 0.5).
// copysign variant is bit-identical: for x!=0, sign(x)*TINY == copysign(TINY,x);
// for x==+-0 both paths floor(+-TINY-ish + 0.5) = 0.
__device__ __forceinline__ float cround(float x) {
#pragma clang fp contract(off)
    float t = x - copysignf(TINY_EPS, x);
    return floorf(t + 0.5f);
}

// One D8 branch candidate: y = f + parity-masked g_x flip.
// DISTANCES ARE NOT COMPUTED HERE. Round-3 bug: deriving the branch-1
// distance from w = xs - f uses the ROUNDED xs = x-0.5 (inexact for
// |x|<0.25), which differs from the reference's (x - y1)^2 by ~1 ulp and
// flips d0<d1 near-ties. The caller computes distances from the original x.
__device__ __forceinline__ void d8_candidate(const float in[8], float y[8]) {
#pragma clang fp contract(off)
    float f[8], w[8];
#pragma unroll
    for (int j = 0; j < 8; ++j) { f[j] = cround(in[j]); w[j] = in[j] - f[j]; }

    // parity of the (exact) integer sum
    float s = ((f[0] + f[1]) + (f[2] + f[3])) + ((f[4] + f[5]) + (f[6] + f[7]));
    int odd = ((int)s) & 1;

    // argmax |w|, FIRST index on ties (np.argmax): descending scan with >=
    float best = fabsf(w[7]); int k = 7; float wk = w[7], xk = in[7];
#pragma unroll
    for (int j = 6; j >= 0; --j) {
        bool ge = (fabsf(w[j]) >= best);   // abs folds into VOP3 modifier
        best = fmaxf(fabsf(w[j]), best);
        k  = ge ? j     : k;
        wk = ge ? w[j]  : wk;
        xk = ge ? in[j] : xk;
    }
    // ref step: xk>=0 ? (fk<xk ? +1:-1) : (fk<=xk ? +1:-1)
    //  == sign(wk) for wk!=0; for wk==0 (integer input): -1 if xk>=0 else +1.
    // w = in - f is exact, so wk>0 <=> fk<xk etc. (xk==-0 with wk==0 is
    // unreachable: no CP input coordinate is -0.0.)
    float tsel = (wk != 0.0f) ? wk : -xk;
    float sf = __int_as_float(0x3f800000 | (__float_as_int(tsel) & 0x80000000u));
    float sfm = odd ? sf : 0.0f;           // flip only when parity is odd
#pragma unroll
    for (int j = 0; j < 8; ++j)
        y[j] = f[j] + ((k == j) ? sfm : 0.0f);
}

__device__ __forceinline__ void closest_point_E8(const float x[8], float y[8]) {
#pragma clang fp contract(off)
    float y0[8], y1[8], xs[8];
    d8_candidate(x, y0);
#pragma unroll
    for (int j = 0; j < 8; ++j) xs[j] = x[j] - 0.5f;
    d8_candidate(xs, y1);
#pragma unroll
    for (int j = 0; j < 8; ++j) y1[j] = y1[j] + 0.5f;   // (candidate)+0.5, as ref

    // Distances from the ORIGINAL x (ref dataflow), numpy pairwise tree.
    float t0[8], t1[8];
#pragma unroll
    for (int j = 0; j < 8; ++j) {
        float d0 = x[j] - y0[j]; t0[j] = d0 * d0;
        float d1 = x[j] - y1[j]; t1[j] = d1 * d1;
    }
    float D0 = ((t0[0] + t0[1]) + (t0[2] + t0[3])) + ((t0[4] + t0[5]) + (t0[6] + t0[7]));
    float D1 = ((t1[0] + t1[1]) + (t1[2] + t1[3])) + ((t1[4] + t1[5]) + (t1[6] + t1[7]));
    bool pick0 = (D0 < D1);                // tie -> y1, as in ref
#pragma unroll
    for (int j = 0; j < 8; ++j) y[j] = pick0 ? y0[j] : y1[j];
}

__global__ __launch_bounds__(256)
void lattice_quant_kernel(const float* __restrict__ x,
                          const float* __restrict__ beta_p,
                          const float* __restrict__ eps,
                          float* __restrict__ out, int n) {
#pragma clang fp contract(off)
    int row = blockIdx.x * blockDim.x + threadIdx.x;
    if (row >= n) return;
    float beta = beta_p[0];

    float xr[8];
    const float4* px = (const float4*)(x + (size_t)row * 8);
    float4 a0 = px[0], a1 = px[1];
    xr[0] = a0.x; xr[1] = a0.y; xr[2] = a0.z; xr[3] = a0.w;
    xr[4] = a1.x; xr[5] = a1.y; xr[6] = a1.z; xr[7] = a1.w;

    float xl[8];
    if (beta == 1.0f) {                    // wave-uniform: skip exact-div seq
#pragma unroll
        for (int j = 0; j < 8; ++j) xl[j] = xr[j];
    } else {
#pragma unroll
        for (int j = 0; j < 8; ++j) xl[j] = xr[j] / beta;
    }

    float xhat[8];
#pragma unroll
    for (int j = 0; j < 8; ++j) xhat[j] = 0.0f;

    float wgt = 1.0f;
#pragma unroll
    for (int l = 0; l < 3; ++l) {
        // ---- encode: quantize to E8 ----
        float xin[8], lat[8];
#pragma unroll
        for (int j = 0; j < 8; ++j) xin[j] = xl[j] + eps[j];
        closest_point_E8(xin, lat);

        // u = lat @ G_inv via forward substitution on lower-triangular `rows`
        // (exact fp32 — quarter-grid values, small; bit-equal to ref matmul)
        float u[8];
        u[0] = 0.5f * lat[0];
#pragma unroll
        for (int k = 1; k <= 6; ++k) u[k] = lat[k] + u[k - 1];
        float s6 = ((u[0] + u[1]) + (u[2] + u[3])) + ((u[4] + u[5]) + u[6]);
        u[7] = 2.0f * lat[7] - s6;

        // b = custom_round(fmod(u, 4)); fmod exact on quarter grid; the fmaf
        // is exact-by-proof (trunc*4 exact), so fused == ref's separate ops.
        float b[8];
#pragma unroll
        for (int j = 0; j < 8; ++j) {
            float t4 = truncf(u[j] * 0.25f);
            float m = __builtin_fmaf(t4, -4.0f, u[j]);
            b[j] = cround(m);
        }

        // ---- decode this layer: Gb = b @ rows (sparse, exact) ----
        float h = 0.5f * b[7];
        float Gb[8];
        Gb[0] = 2.0f * b[0] - b[1] + h;
#pragma unroll
        for (int j = 1; j <= 5; ++j) Gb[j] = b[j] - b[j + 1] + h;
        Gb[6] = b[6] + h;
        Gb[7] = h;

        float gq[8], cp[8];
#pragma unroll
        for (int j = 0; j < 8; ++j) gq[j] = Gb[j] * 0.25f;
        closest_point_E8(gq, cp);
#pragma unroll
        for (int j = 0; j < 8; ++j) {
            float xi = __builtin_fmaf(-4.0f, cp[j], Gb[j]);   // 4*cp exact
            xhat[j] = __builtin_fmaf(wgt, xi, xhat[j]);       // wgt*xi exact
        }

        // next layer input: lat / Q (exact)
#pragma unroll
        for (int j = 0; j < 8; ++j) xl[j] = lat[j] * 0.25f;
        wgt *= 4.0f;
    }

    float4 o0, o1;
    o0.x = beta * xhat[0]; o0.y = beta * xhat[1];
    o0.z = beta * xhat[2]; o0.w = beta * xhat[3];
    o1.x = beta * xhat[4]; o1.y = beta * xhat[5];
    o1.z = beta * xhat[6]; o1.w = beta * xhat[7];
    float4* po = (float4*)(out + (size_t)row * 8);
    po[0] = o0; po[1] = o1;
}

extern "C" void kernel_launch(void* const* d_in, const int* in_sizes, int n_in,
                              void* d_out, int out_size, void* d_ws, size_t ws_size,
                              hipStream_t stream) {
    const float* x      = (const float*)d_in[0];
    const float* beta_p = (const float*)d_in[1];
    // d_in[2] = G, d_in[3] = G_inv — structure hardcoded (fixed by reference)
    const float* eps    = (const float*)d_in[4];
    float* out = (float*)d_out;
    int n = in_sizes[0] / 8;
    int block = 256;
    int grid = (n + block - 1) / block;
    lattice_quant_kernel<<<grid, block, 0, stream>>>(x, beta_p, eps, out, n);
}

// Round 5
// 334.501 us; speedup vs baseline: 1.1748x; 1.0856x over previous
//
#include <hip/hip_runtime.h>
#include <math.h>

#define TINY_EPS 1.1920928955078125e-07f  // np.finfo(np.float32).eps = 2^-23

typedef float float2v __attribute__((ext_vector_type(2)));

// Packed fma helper — per-component IEEE fma; SLP-forms v_pk_fma_f32.
static __device__ __forceinline__ float2v fma2(float2v a, float2v b, float2v c) {
#pragma clang fp contract(off)
    float2v r;
    r.x = __builtin_fmaf(a.x, b.x, c.x);
    r.y = __builtin_fmaf(a.y, b.y, c.y);
    return r;
}

// custom_round per component: floor(x - copysign(TINY,x) + 0.5).
// sub and +0.5 pack (v_pk_add_f32); copysign (v_bfi) and floor stay scalar.
static __device__ __forceinline__ float2v croundv(float2v v) {
#pragma clang fp contract(off)
    float2v cs;
    cs.x = copysignf(TINY_EPS, v.x);
    cs.y = copysignf(TINY_EPS, v.y);
    float2v t = v - cs;
    t = t + 0.5f;
    float2v f;
    f.x = floorf(t.x);
    f.y = floorf(t.y);
    return f;
}

// One D8 branch candidate: y = f + parity-masked g_x flip (no distances here —
// caller computes them from the ORIGINAL x, matching the reference dataflow).
static __device__ __forceinline__ void d8_candidate(const float2v in[4], float2v y[4]) {
#pragma clang fp contract(off)
    float2v f[4], w[4];
#pragma unroll
    for (int p = 0; p < 4; ++p) { f[p] = croundv(in[p]); w[p] = in[p] - f[p]; }

    // parity of the integer sum — exact small ints, order-free -> packed tree
    float2v sp = (f[0] + f[1]) + (f[2] + f[3]);
    float s = sp.x + sp.y;
    int odd = ((int)s) & 1;

    // argmax |w|, FIRST index on ties: descending scan with >=.
    // best == |wk| invariant -> no separate best carry (abs folds into VOP3
    // modifiers). xk carry dropped: wk==0 => max|w|==0 => all w==0 => k==0,
    // so the tie-case x value is in[0].x (never -0.0 — proven for all CP
    // inputs: x+eps, x-0.5, Gb/4 produce +0 at zero).
    int k = 7; float wk = w[3].y;
    { bool ge = (fabsf(w[3].x) >= fabsf(wk)); k = ge ? 6 : k; wk = ge ? w[3].x : wk; }
    { bool ge = (fabsf(w[2].y) >= fabsf(wk)); k = ge ? 5 : k; wk = ge ? w[2].y : wk; }
    { bool ge = (fabsf(w[2].x) >= fabsf(wk)); k = ge ? 4 : k; wk = ge ? w[2].x : wk; }
    { bool ge = (fabsf(w[1].y) >= fabsf(wk)); k = ge ? 3 : k; wk = ge ? w[1].y : wk; }
    { bool ge = (fabsf(w[1].x) >= fabsf(wk)); k = ge ? 2 : k; wk = ge ? w[1].x : wk; }
    { bool ge = (fabsf(w[0].y) >= fabsf(wk)); k = ge ? 1 : k; wk = ge ? w[0].y : wk; }
    { bool ge = (fabsf(w[0].x) >= fabsf(wk)); k = ge ? 0 : k; wk = ge ? w[0].x : wk; }

    // step = sign(wk) for wk!=0; for wk==0: -1 if in[0]>=0 else +1.
    float tsel = (wk != 0.0f) ? wk : -in[0].x;
    float sf = __int_as_float(0x3f800000 | (__float_as_int(tsel) & 0x80000000u));
    float sfm = odd ? sf : 0.0f;           // flip only when parity is odd

#pragma unroll
    for (int p = 0; p < 4; ++p) {
        float2v c;
        c.x = (k == 2 * p)     ? sfm : 0.0f;
        c.y = (k == 2 * p + 1) ? sfm : 0.0f;
        y[p] = f[p] + c;
    }
}

static __device__ __forceinline__ void closest_point_E8v(const float2v x[4], float2v y[4]) {
#pragma clang fp contract(off)
    float2v y0[4], y1[4], xs[4];
    d8_candidate(x, y0);
#pragma unroll
    for (int p = 0; p < 4; ++p) xs[p] = x[p] - 0.5f;
    d8_candidate(xs, y1);
#pragma unroll
    for (int p = 0; p < 4; ++p) y1[p] = y1[p] + 0.5f;   // (candidate)+0.5, as ref

    // Distances from the ORIGINAL x; packed subs/squares, scalar tree adds in
    // numpy's exact pairwise order ((t0+t1)+(t2+t3))+((t4+t5)+(t6+t7)) —
    // the vector-element pairs ARE the numpy base pairs.
    float2v q0[4], q1[4];
#pragma unroll
    for (int p = 0; p < 4; ++p) {
        float2v e0 = x[p] - y0[p]; q0[p] = e0 * e0;
        float2v e1 = x[p] - y1[p]; q1[p] = e1 * e1;
    }
    float D0 = ((q0[0].x + q0[0].y) + (q0[1].x + q0[1].y)) +
               ((q0[2].x + q0[2].y) + (q0[3].x + q0[3].y));
    float D1 = ((q1[0].x + q1[0].y) + (q1[1].x + q1[1].y)) +
               ((q1[2].x + q1[2].y) + (q1[3].x + q1[3].y));
    bool pick0 = (D0 < D1);                // tie -> y1, as in ref
#pragma unroll
    for (int p = 0; p < 4; ++p) y[p] = pick0 ? y0[p] : y1[p];
}

__global__ __launch_bounds__(256)
void lattice_quant_kernel(const float* __restrict__ x,
                          const float* __restrict__ beta_p,
                          const float* __restrict__ eps,
                          float* __restrict__ out, int n) {
#pragma clang fp contract(off)
    int row = blockIdx.x * blockDim.x + threadIdx.x;
    if (row >= n) return;
    float beta = beta_p[0];

    const float4* px = (const float4*)(x + (size_t)row * 8);
    float4 a0 = px[0], a1 = px[1];
    const float4* pe = (const float4*)eps;
    float4 e0 = pe[0], e1 = pe[1];
    float2v eps2[4] = { {e0.x, e0.y}, {e0.z, e0.w}, {e1.x, e1.y}, {e1.z, e1.w} };

    float2v xl[4] = { {a0.x, a0.y}, {a0.z, a0.w}, {a1.x, a1.y}, {a1.z, a1.w} };
    if (beta != 1.0f) {                    // wave-uniform; beta==1 skips divs
#pragma unroll
        for (int p = 0; p < 4; ++p) { xl[p].x = xl[p].x / beta; xl[p].y = xl[p].y / beta; }
    }

    float2v xhat[4];
#pragma unroll
    for (int p = 0; p < 4; ++p) xhat[p] = (float2v){0.0f, 0.0f};

    const float2v n4 = {-4.0f, -4.0f};
    float wgt = 1.0f;
#pragma unroll
    for (int l = 0; l < 3; ++l) {
        // ---- encode: quantize to E8 ----
        float2v xin[4], lat[4];
#pragma unroll
        for (int p = 0; p < 4; ++p) xin[p] = xl[p] + eps2[p];
        closest_point_E8v(xin, lat);

        // u = lat @ G_inv via forward substitution (exact fp32 == ref matmul)
        float u0 = 0.5f * lat[0].x;
        float u1 = lat[0].y + u0;
        float u2 = lat[1].x + u1;
        float u3 = lat[1].y + u2;
        float u4 = lat[2].x + u3;
        float u5 = lat[2].y + u4;
        float u6 = lat[3].x + u5;
        float s6 = ((u0 + u1) + (u2 + u3)) + ((u4 + u5) + u6);
        float u7 = 2.0f * lat[3].y - s6;
        float2v uv[4] = { {u0, u1}, {u2, u3}, {u4, u5}, {u6, u7} };

        // b = custom_round(fmod(u, 4)); fmod exact on quarter grid; the fma
        // is exact-by-proof (trunc*4 exact), so fused == ref's separate ops.
        float2v b[4];
#pragma unroll
        for (int p = 0; p < 4; ++p) {
            float2v q = uv[p] * 0.25f;
            float2v t4; t4.x = truncf(q.x); t4.y = truncf(q.y);
            float2v m = fma2(t4, n4, uv[p]);
            b[p] = croundv(m);
        }

        // ---- decode this layer: Gb = b @ rows (sparse, exact) ----
        float b0 = b[0].x, b1 = b[0].y, b2 = b[1].x, b3 = b[1].y;
        float b4 = b[2].x, b5 = b[2].y, b6 = b[3].x, b7 = b[3].y;
        float h = 0.5f * b7;
        float2v Gb[4];
        Gb[0].x = 2.0f * b0 - b1 + h;
        Gb[0].y = b1 - b2 + h;
        Gb[1].x = b2 - b3 + h;
        Gb[1].y = b3 - b4 + h;
        Gb[2].x = b4 - b5 + h;
        Gb[2].y = b5 - b6 + h;
        Gb[3].x = b6 + h;
        Gb[3].y = h;

        float2v gq[4], cp[4];
#pragma unroll
        for (int p = 0; p < 4; ++p) gq[p] = Gb[p] * 0.25f;
        closest_point_E8v(gq, cp);

        float2v wv = {wgt, wgt};
#pragma unroll
        for (int p = 0; p < 4; ++p) {
            float2v xi = fma2(n4, cp[p], Gb[p]);   // Gb - 4*cp, 4*cp exact
            xhat[p] = fma2(wv, xi, xhat[p]);       // wgt*xi exact
        }

        // next layer input: lat / Q (exact)
#pragma unroll
        for (int p = 0; p < 4; ++p) xl[p] = lat[p] * 0.25f;
        wgt *= 4.0f;
    }

    float2v o[4];
#pragma unroll
    for (int p = 0; p < 4; ++p) o[p] = xhat[p] * beta;
    float4 o0, o1;
    o0.x = o[0].x; o0.y = o[0].y; o0.z = o[1].x; o0.w = o[1].y;
    o1.x = o[2].x; o1.y = o[2].y; o1.z = o[3].x; o1.w = o[3].y;
    float4* po = (float4*)(out + (size_t)row * 8);
    po[0] = o0; po[1] = o1;
}

extern "C" void kernel_launch(void* const* d_in, const int* in_sizes, int n_in,
                              void* d_out, int out_size, void* d_ws, size_t ws_size,
                              hipStream_t stream) {
    const float* x      = (const float*)d_in[0];
    const float* beta_p = (const float*)d_in[1];
    // d_in[2] = G, d_in[3] = G_inv — structure hardcoded (fixed by reference)
    const float* eps    = (const float*)d_in[4];
    float* out = (float*)d_out;
    int n = in_sizes[0] / 8;
    int block = 256;
    int grid = (n + block - 1) / block;
    lattice_quant_kernel<<<grid, block, 0, stream>>>(x, beta_p, eps, out, n);
}

// Round 6
// 332.988 us; speedup vs baseline: 1.1801x; 1.0045x over previous
//
#include <hip/hip_runtime.h>
#include <math.h>

#define TINY_EPS 1.1920928955078125e-07f  // np.finfo(np.float32).eps = 2^-23

typedef float float2v __attribute__((ext_vector_type(2)));

// ---- forced VOP3P packed fp32 ops (2 IEEE fp32 ops per issue slot) ----
// Each is per-component bit-identical to the scalar op it replaces.
static __device__ __forceinline__ float2v pk_add(float2v a, float2v b) {
    float2v d;
    asm("v_pk_add_f32 %0, %1, %2" : "=v"(d) : "v"(a), "v"(b));
    return d;
}
static __device__ __forceinline__ float2v pk_mul(float2v a, float2v b) {
    float2v d;
    asm("v_pk_mul_f32 %0, %1, %2" : "=v"(d) : "v"(a), "v"(b));
    return d;
}
static __device__ __forceinline__ float2v pk_fma(float2v a, float2v b, float2v c) {
    float2v d;
    asm("v_pk_fma_f32 %0, %1, %2, %3" : "=v"(d) : "v"(a), "v"(b), "v"(c));
    return d;
}
static __device__ __forceinline__ void pk_fma_acc(float2v& c, float2v a, float2v b) {
    asm("v_pk_fma_f32 %0, %1, %2, %0" : "+v"(c) : "v"(a), "v"(b));
}

struct PkConsts {
    float2v neg1, half, neghalf, neg4, quarter;
};

// custom_round per component: floor((x - copysign(TINY,x)) + 0.5).
// pk_fma(cs,-1,v) == fl(v-cs) (single rounding, identical to IEEE sub).
static __device__ __forceinline__ float2v croundv(float2v v, const PkConsts& C) {
#pragma clang fp contract(off)
    float2v cs;
    cs.x = copysignf(TINY_EPS, v.x);
    cs.y = copysignf(TINY_EPS, v.y);
    float2v t = pk_fma(cs, C.neg1, v);   // v - cs
    t = pk_add(t, C.half);               // + 0.5
    float2v f;
    f.x = floorf(t.x);
    f.y = floorf(t.y);
    return f;
}

// One D8 branch candidate: y = f + parity-masked g_x flip. Distances are NOT
// computed here — the caller computes them from the ORIGINAL x (ref dataflow).
static __device__ __forceinline__ void d8_candidate(const float2v in[4], float2v y[4],
                                                    const PkConsts& C) {
#pragma clang fp contract(off)
    float2v f[4], w[4];
#pragma unroll
    for (int p = 0; p < 4; ++p) {
        f[p] = croundv(in[p], C);
        w[p] = pk_fma(f[p], C.neg1, in[p]);   // in - f (exact)
    }

    // parity of the integer sum — exact small ints, order-free
    float2v sp = pk_add(pk_add(f[0], f[1]), pk_add(f[2], f[3]));
    float s = sp.x + sp.y;
    int odd = ((int)s) & 1;

    // argmax |w|, FIRST index on ties: descending scan with >= (abs folds
    // into VOP3 modifiers; best == |wk| invariant; xk carry dropped — wk==0
    // implies all-zero w so k==0 and the tie x-value is in[0].x, never -0.0).
    int k = 7; float wk = w[3].y;
    { bool ge = (fabsf(w[3].x) >= fabsf(wk)); k = ge ? 6 : k; wk = ge ? w[3].x : wk; }
    { bool ge = (fabsf(w[2].y) >= fabsf(wk)); k = ge ? 5 : k; wk = ge ? w[2].y : wk; }
    { bool ge = (fabsf(w[2].x) >= fabsf(wk)); k = ge ? 4 : k; wk = ge ? w[2].x : wk; }
    { bool ge = (fabsf(w[1].y) >= fabsf(wk)); k = ge ? 3 : k; wk = ge ? w[1].y : wk; }
    { bool ge = (fabsf(w[1].x) >= fabsf(wk)); k = ge ? 2 : k; wk = ge ? w[1].x : wk; }
    { bool ge = (fabsf(w[0].y) >= fabsf(wk)); k = ge ? 1 : k; wk = ge ? w[0].y : wk; }
    { bool ge = (fabsf(w[0].x) >= fabsf(wk)); k = ge ? 0 : k; wk = ge ? w[0].x : wk; }

    // step = sign(wk) for wk!=0; for wk==0: -1 if in[0]>=0 else +1.
    float tsel = (wk != 0.0f) ? wk : -in[0].x;
    float sf = __int_as_float(0x3f800000 | (__float_as_int(tsel) & 0x80000000u));
    float sfm = odd ? sf : 0.0f;          // flip only when parity is odd

#pragma unroll
    for (int p = 0; p < 4; ++p) {
        float2v c;
        c.x = (k == 2 * p)     ? sfm : 0.0f;
        c.y = (k == 2 * p + 1) ? sfm : 0.0f;
        y[p] = pk_add(f[p], c);
    }
}

static __device__ __forceinline__ void closest_point_E8v(const float2v x[4], float2v y[4],
                                                         const PkConsts& C) {
#pragma clang fp contract(off)
    float2v y0[4], y1[4], xs[4];
    d8_candidate(x, y0, C);
#pragma unroll
    for (int p = 0; p < 4; ++p) xs[p] = pk_add(x[p], C.neghalf);   // x - 0.5
    d8_candidate(xs, y1, C);
#pragma unroll
    for (int p = 0; p < 4; ++p) y1[p] = pk_add(y1[p], C.half);     // (cand)+0.5

    // Distances from the ORIGINAL x; packed subs/squares, scalar tree adds in
    // numpy's exact pairwise order — vector-element pairs ARE the base pairs.
    float2v q0[4], q1[4];
#pragma unroll
    for (int p = 0; p < 4; ++p) {
        float2v e0 = pk_fma(y0[p], C.neg1, x[p]);  // x - y0
        q0[p] = pk_mul(e0, e0);
        float2v e1 = pk_fma(y1[p], C.neg1, x[p]);  // x - y1
        q1[p] = pk_mul(e1, e1);
    }
    float D0 = ((q0[0].x + q0[0].y) + (q0[1].x + q0[1].y)) +
               ((q0[2].x + q0[2].y) + (q0[3].x + q0[3].y));
    float D1 = ((q1[0].x + q1[0].y) + (q1[1].x + q1[1].y)) +
               ((q1[2].x + q1[2].y) + (q1[3].x + q1[3].y));
    bool pick0 = (D0 < D1);               // tie -> y1, as in ref
#pragma unroll
    for (int p = 0; p < 4; ++p) {
        float2v r;
        r.x = pick0 ? y0[p].x : y1[p].x;
        r.y = pick0 ? y0[p].y : y1[p].y;
        y[p] = r;
    }
}

__global__ __launch_bounds__(256)
void lattice_quant_kernel(const float* __restrict__ x,
                          const float* __restrict__ beta_p,
                          const float* __restrict__ eps,
                          float* __restrict__ out, int n) {
#pragma clang fp contract(off)
    int row = blockIdx.x * blockDim.x + threadIdx.x;
    if (row >= n) return;
    float beta = beta_p[0];

    PkConsts C;
    C.neg1    = (float2v){-1.0f, -1.0f};
    C.half    = (float2v){ 0.5f,  0.5f};
    C.neghalf = (float2v){-0.5f, -0.5f};
    C.neg4    = (float2v){-4.0f, -4.0f};
    C.quarter = (float2v){ 0.25f, 0.25f};

    const float4* px = (const float4*)(x + (size_t)row * 8);
    float4 a0 = px[0], a1 = px[1];
    const float4* pe = (const float4*)eps;
    float4 e0 = pe[0], e1 = pe[1];
    float2v eps2[4] = { {e0.x, e0.y}, {e0.z, e0.w}, {e1.x, e1.y}, {e1.z, e1.w} };

    float2v xl[4] = { {a0.x, a0.y}, {a0.z, a0.w}, {a1.x, a1.y}, {a1.z, a1.w} };
    if (beta != 1.0f) {                   // wave-uniform; beta==1 skips divs
#pragma unroll
        for (int p = 0; p < 4; ++p) { xl[p].x = xl[p].x / beta; xl[p].y = xl[p].y / beta; }
    }

    float2v xhat[4];
#pragma unroll
    for (int p = 0; p < 4; ++p) xhat[p] = (float2v){0.0f, 0.0f};

    float wgt = 1.0f;
#pragma unroll
    for (int l = 0; l < 3; ++l) {
        // ---- encode: quantize to E8 ----
        float2v xin[4], lat[4];
#pragma unroll
        for (int p = 0; p < 4; ++p) xin[p] = pk_add(xl[p], eps2[p]);
        closest_point_E8v(xin, lat, C);

        // u = lat @ G_inv via forward substitution (exact fp32 == ref matmul)
        float u0 = 0.5f * lat[0].x;
        float u1 = lat[0].y + u0;
        float u2 = lat[1].x + u1;
        float u3 = lat[1].y + u2;
        float u4 = lat[2].x + u3;
        float u5 = lat[2].y + u4;
        float u6 = lat[3].x + u5;
        float s6 = ((u0 + u1) + (u2 + u3)) + ((u4 + u5) + u6);
        float u7 = 2.0f * lat[3].y - s6;
        float2v uv[4] = { {u0, u1}, {u2, u3}, {u4, u5}, {u6, u7} };

        // b = custom_round(fmod(u, 4)); fmod exact on quarter grid; the fma
        // is exact-by-proof (trunc*4 exact), so fused == ref's separate ops.
        float2v b[4];
#pragma unroll
        for (int p = 0; p < 4; ++p) {
            float2v q = pk_mul(uv[p], C.quarter);
            float2v t4; t4.x = truncf(q.x); t4.y = truncf(q.y);
            float2v m = pk_fma(t4, C.neg4, uv[p]);
            b[p] = croundv(m, C);
        }

        // ---- decode this layer: Gb = b @ rows (sparse, exact ints) ----
        float b0 = b[0].x, b1 = b[0].y, b2 = b[1].x, b3 = b[1].y;
        float b4 = b[2].x, b5 = b[2].y, b6 = b[3].x, b7 = b[3].y;
        float h = 0.5f * b7;
        float2v Gb[4];
        Gb[0].x = 2.0f * b0 - b1 + h;
        Gb[0].y = b1 - b2 + h;
        Gb[1].x = b2 - b3 + h;
        Gb[1].y = b3 - b4 + h;
        Gb[2].x = b4 - b5 + h;
        Gb[2].y = b5 - b6 + h;
        Gb[3].x = b6 + h;
        Gb[3].y = h;

        float2v gq[4], cp[4];
#pragma unroll
        for (int p = 0; p < 4; ++p) gq[p] = pk_mul(Gb[p], C.quarter);
        closest_point_E8v(gq, cp, C);

        float2v wv = {wgt, wgt};
#pragma unroll
        for (int p = 0; p < 4; ++p) {
            float2v xi = pk_fma(cp[p], C.neg4, Gb[p]);  // Gb - 4*cp (exact)
            pk_fma_acc(xhat[p], xi, wv);                // += wgt*xi (exact)
        }

        // next layer input: lat / Q (exact)
#pragma unroll
        for (int p = 0; p < 4; ++p) xl[p] = pk_mul(lat[p], C.quarter);
        wgt *= 4.0f;
    }

    float2v o[4];
#pragma unroll
    for (int p = 0; p < 4; ++p) { o[p].x = xhat[p].x * beta; o[p].y = xhat[p].y * beta; }
    float4 o0, o1;
    o0.x = o[0].x; o0.y = o[0].y; o0.z = o[1].x; o0.w = o[1].y;
    o1.x = o[2].x; o1.y = o[2].y; o1.z = o[3].x; o1.w = o[3].y;
    float4* po = (float4*)(out + (size_t)row * 8);
    po[0] = o0; po[1] = o1;
}

extern "C" void kernel_launch(void* const* d_in, const int* in_sizes, int n_in,
                              void* d_out, int out_size, void* d_ws, size_t ws_size,
                              hipStream_t stream) {
    const float* x      = (const float*)d_in[0];
    const float* beta_p = (const float*)d_in[1];
    // d_in[2] = G, d_in[3] = G_inv — structure hardcoded (fixed by reference)
    const float* eps    = (const float*)d_in[4];
    float* out = (float*)d_out;
    int n = in_sizes[0] / 8;
    int block = 256;
    int grid = (n + block - 1) / block;
    lattice_quant_kernel<<<grid, block, 0, stream>>>(x, beta_p, eps, out, n);
}